// Round 4
// baseline (142.985 us; speedup 1.0000x reference)
//
#include <hip/hip_runtime.h>
#include <hip/hip_bf16.h>

// R12 = R11 with:
//  - attn: 32 q-rows per wave (two 16-q B-fragments sharing each K/V LDS read),
//    2 waves per block, grid still 768 (3 blocks/CU exact). Halves LDS-read
//    bytes per q (the R10/R11 null results point at LDS *bytes* as the bound).
//  - QKV GEMM: TM=128 @ 4 waves, grid (64,9)=576 blocks (was 288@8w = 1.125/CU
//    with a 32-CU straggler tail; 576@4w rebalances to 2.25/CU).
// All layouts (qg row-major *QSCALE, kg operand-order, vg shuffle-permuted
// mfma32 order) unchanged from R11. ws layout unchanged: 32.5 MB.

typedef __attribute__((__ext_vector_type__(8))) __bf16 bf16x8;
typedef __attribute__((__ext_vector_type__(8))) unsigned short ushort8;
typedef __attribute__((__ext_vector_type__(4))) unsigned short ushort4v;
typedef __attribute__((__ext_vector_type__(4))) short short4v;
typedef __attribute__((__ext_vector_type__(4))) float f32x4;

#define NX 3145728   // 8192*384
#define NQ 442368    // 1152*384
#define NP 147456    // 384*384

// 0.125 * log2(e): folds the exp->exp2 conversion into the Q scale.
#define QSCALE 0.1803368801111204f

__device__ __forceinline__ f32x4 mfma32(bf16x8 a, bf16x8 b, f32x4 c) {
    return __builtin_amdgcn_mfma_f32_16x16x32_bf16(a, b, c, 0, 0, 0);
}

__device__ __forceinline__ unsigned short f2bf(float f) {
    union { float f; unsigned int i; } x; x.f = f;
    unsigned int u = x.i;
    return (unsigned short)((u + 0x7fffu + ((u >> 16) & 1u)) >> 16);
}

// pack two f32 -> one u32 of 2 bf16 (RNE) on the VALU cvt pipe
__device__ __forceinline__ unsigned cvtpk(float a, float b) {
    unsigned r;
    asm("v_cvt_pk_bf16_f32 %0, %1, %2" : "=v"(r) : "v"(a), "v"(b));
    return r;
}

__device__ __forceinline__ void dma16(const unsigned short* g, unsigned short* l) {
    __builtin_amdgcn_global_load_lds(
        (const __attribute__((address_space(1))) unsigned int*)g,
        (__attribute__((address_space(3))) unsigned int*)l, 16, 0, 0);
}

// fp32 -> bf16 for x, w_qkv, w_proj. 4 elems/thread.
__global__ __launch_bounds__(256) void cvt_bf16(
    const float* __restrict__ x, const float* __restrict__ wq, const float* __restrict__ wp,
    unsigned short* __restrict__ xb, unsigned short* __restrict__ wqb, unsigned short* __restrict__ wpb)
{
    int i = blockIdx.x * 256 + threadIdx.x;
    const float* src; unsigned short* dst; int off;
    if (i < NX / 4)              { src = x;  dst = xb;  off = i * 4; }
    else if (i < (NX + NQ) / 4)  { src = wq; dst = wqb; off = i * 4 - NX; }
    else                         { src = wp; dst = wpb; off = i * 4 - NX - NQ; }
    float4 v = *(const float4*)(src + off);
    ushort4v r;
    r[0] = f2bf(v.x); r[1] = f2bf(v.y); r[2] = f2bf(v.z); r[3] = f2bf(v.w);
    *(ushort4v*)(dst + off) = r;
}

// C = A[M,K] @ B[N,K]^T + bias. bf16 in, fp32 acc, TMx128 tile, BK=32.
// Single-barrier double-buffered DMA pipeline. THREADS = 2*TM.
// MODE 0 (QKV): n<384 -> qg row-major *QSCALE ; 384..768 -> kg operand-order ;
//               >=768 -> vg in the shuffle-permuted mfma32-PV operand order.
// MODE 1 (proj): fp32 out + bias.
template <int MODE, int TM>
__global__ __launch_bounds__(TM * 2) void gemm_bt(
    const unsigned short* __restrict__ A,
    const unsigned short* __restrict__ B,
    const float* __restrict__ bias,
    unsigned short* __restrict__ qg,
    unsigned short* __restrict__ kg,
    unsigned short* __restrict__ vg,
    float* __restrict__ out,
    int M, int N, int K)
{
    const int tid  = threadIdx.x;
    const int lane = tid & 63;
    const int wave = tid >> 6;
    const int l15  = lane & 15;
    const int quad = lane >> 4;
    const int m0 = blockIdx.x * TM;
    const int n0 = blockIdx.y * 128;
    const int wm = (wave >> 1) * 64;
    const int wn = (wave & 1) * 64;

    __shared__ __align__(16) unsigned short As[2 * TM * 32];
    __shared__ __align__(16) unsigned short Bs[2 * 128 * 32];

    f32x4 acc[4][4];
    #pragma unroll
    for (int i = 0; i < 4; ++i)
        #pragma unroll
        for (int j = 0; j < 4; ++j)
            acc[i][j] = (f32x4){0.f, 0.f, 0.f, 0.f};

    // stage K-slice k0 into buffer buf
    auto stage = [&](int k0, int buf) {
        #pragma unroll
        for (int t = 0; t < 2; ++t) {
            int i = tid + t * TM * 2;
            dma16(A + (size_t)(m0 + (i >> 2)) * K + k0 + (i & 3) * 8,
                  As + buf * TM * 32 + t * TM * 16 + wave * 512);
        }
        #pragma unroll
        for (int t = 0; t < 512 / (TM * 2); ++t) {
            int i = tid + t * TM * 2;
            dma16(B + (size_t)(n0 + (i >> 2)) * K + k0 + (i & 3) * 8,
                  Bs + buf * 4096 + t * TM * 16 + wave * 512);
        }
    };

    const int nk = K >> 5;   // 12
    stage(0, 0);
    for (int ki = 0; ki < nk; ++ki) {
        __syncthreads();                       // drains DMA for buf ki&1; syncs compute ki-1
        if (ki + 1 < nk) stage((ki + 1) << 5, (ki + 1) & 1);   // in flight during compute
        const unsigned short* as = As + (ki & 1) * TM * 32;
        const unsigned short* bs = Bs + (ki & 1) * 4096;

        bf16x8 af[4], bff[4];
        #pragma unroll
        for (int mt = 0; mt < 4; ++mt)
            af[mt] = *(const bf16x8*)(as + (wm + mt * 16 + l15) * 32 + quad * 8);
        #pragma unroll
        for (int nt = 0; nt < 4; ++nt)
            bff[nt] = *(const bf16x8*)(bs + (wn + nt * 16 + l15) * 32 + quad * 8);
        #pragma unroll
        for (int mt = 0; mt < 4; ++mt)
            #pragma unroll
            for (int nt = 0; nt < 4; ++nt)
                acc[mt][nt] = mfma32(af[mt], bff[nt], acc[mt][nt]);
    }

    if constexpr (MODE == 0) {
        if (n0 < 384) {            // Q region: row-major, pre-scaled by 0.125*log2e
            #pragma unroll
            for (int nt = 0; nt < 4; ++nt) {
                int n = n0 + wn + nt * 16 + l15;
                float bv = bias[n];
                #pragma unroll
                for (int mt = 0; mt < 4; ++mt) {
                    int mbase = m0 + wm + mt * 16 + quad * 4;
                    #pragma unroll
                    for (int r = 0; r < 4; ++r)
                        qg[(size_t)(mbase + r) * 384 + n] = f2bf((acc[mt][nt][r] + bv) * QSCALE);
                }
            }
        } else if (n0 < 768) {     // K region: operand-order slabs
            #pragma unroll
            for (int nt = 0; nt < 4; ++nt) {
                int n = n0 + wn + nt * 16 + l15;
                float bv = bias[n];
                int c2 = n - 384;
                int h = c2 >> 6, ck = c2 & 63;
                int half = ck >> 5, qd = (ck >> 3) & 3, j = ck & 7;
                #pragma unroll
                for (int mt = 0; mt < 4; ++mt) {
                    int mbase = m0 + wm + mt * 16 + quad * 4;
                    #pragma unroll
                    for (int r = 0; r < 4; ++r) {
                        int tok = mbase + r;
                        int b = tok >> 10, kv = tok & 1023;
                        int kt = kv >> 4, lk = kv & 15;
                        kg[(size_t)(b * 6 + h) * 65536 +
                           ((((size_t)kt * 2 + half) * 4 + qd) * 16 + lk) * 8 + j]
                            = f2bf(acc[mt][nt][r] + bv);
                    }
                }
            }
        } else {                   // V region: shuffle-permuted mfma32 operand order
            #pragma unroll
            for (int nt = 0; nt < 4; ++nt) {
                int n = n0 + wn + nt * 16 + l15;
                float bv = bias[n];
                int c2 = n - 768;
                int h = c2 >> 6, d = c2 & 63;
                int dt = d >> 4, lv = d & 15;
                #pragma unroll
                for (int mt = 0; mt < 4; ++mt) {
                    int mbase = m0 + wm + mt * 16 + quad * 4;   // multiple of 4
                    int b = mbase >> 10, kvb = mbase & 1023;
                    int cc = kvb >> 6;
                    int hh = (kvb >> 5) & 1;
                    int rem2 = kvb & 31;                         // multiple of 4
                    int qv, j;
                    if (rem2 < 16) { qv = (rem2 >> 3) << 1; j = rem2 & 7; }
                    else {
                        int m2 = rem2 - 16;
                        qv = 1 + ((m2 >> 3) << 1);
                        j = (((m2 >> 2) & 1) ^ 1) << 2;          // m2 multiple of 4
                    }
                    ushort4v pk;
                    #pragma unroll
                    for (int r = 0; r < 4; ++r) pk[r] = f2bf(acc[mt][nt][r] + bv);
                    *(ushort4v*)(vg + (size_t)(b * 6 + h) * 65536 +
                                 ((((size_t)cc * 2 + hh) * 4 + dt) * 4 + qv) * 128 + lv * 8 + j) = pk;
                }
            }
        }
    } else {
        #pragma unroll
        for (int nt = 0; nt < 4; ++nt) {
            int n = n0 + wn + nt * 16 + l15;
            float bv = bias[n];
            #pragma unroll
            for (int mt = 0; mt < 4; ++mt) {
                int mbase = m0 + wm + mt * 16 + quad * 4;
                #pragma unroll
                for (int r = 0; r < 4; ++r)
                    out[(size_t)(mbase + r) * N + n] = acc[mt][nt][r] + bv;
            }
        }
    }
}

// Flash attention: 2 waves x 32 q-rows (two 16-q fragments per wave), so each
// K/V LDS read serves 32 q (halved LDS-read bytes vs 16 q/wave). Grid 768
// (3 blocks/CU exact), slab-XCD swizzle unchanged. kv-chunk 64, dbuf DMA.
// Per 32-kv half: 4 shared K b128 reads -> 8 QK mfma (2 frags) -> 16 exp2+mask
// -> 8 cvt_pk -> 4 shfl_xor -> 2 rowsum mfma + 8 PV mfma (4 shared V b128).
__global__ __launch_bounds__(128) void attn_fused(
    const unsigned short* __restrict__ qg,
    const unsigned short* __restrict__ kg,
    const unsigned short* __restrict__ vg,
    unsigned short* __restrict__ aout)   // [8192][384] bf16
{
    const int tid  = threadIdx.x;
    const int wave = tid >> 6;           // 0..1
    const int lane = tid & 63;
    const int l15  = lane & 15;
    const int quad = lane >> 4;
    const int id = blockIdx.x;
    const int s  = id % 48;      // slab = b*6+h  (id%8 == s%8 -> same XCD per slab)
    const int qt = id / 48;      // 0..15
    const int b  = s / 6;
    const int h  = s % 6;

    const size_t rowbase = (size_t)b * 1024;
    const unsigned short* Kslab = kg + (size_t)s * 65536;
    const unsigned short* Vslab = vg + (size_t)s * 65536;
    const int q0 = qt * 64 + wave * 32;  // this wave's 32 q-rows

    __shared__ __align__(16) unsigned short Kb[2 * 4096];
    __shared__ __align__(16) unsigned short Vb[2 * 4096];

    // Q fragments: f=0 -> rows q0..q0+15, f=1 -> q0+16..q0+31
    bf16x8 aq0_0, aq1_0, aq0_1, aq1_1;
    {
        const unsigned short* qr0 = qg + (rowbase + q0 + l15) * 384 + h * 64 + quad * 8;
        aq0_0 = *(const bf16x8*)qr0;
        aq1_0 = *(const bf16x8*)(qr0 + 32);
        const unsigned short* qr1 = qr0 + 16 * 384;
        aq0_1 = *(const bf16x8*)qr1;
        aq1_1 = *(const bf16x8*)(qr1 + 32);
    }

    union { unsigned short us[8]; bf16x8 v; } ones_u;
    #pragma unroll
    for (int i = 0; i < 8; ++i) ones_u.us[i] = 0x3F80;
    const bf16x8 ONES8 = ones_u.v;

    f32x4 accO0[4], accO1[4];
    #pragma unroll
    for (int dt = 0; dt < 4; ++dt) {
        accO0[dt] = (f32x4){0.f, 0.f, 0.f, 0.f};
        accO1[dt] = (f32x4){0.f, 0.f, 0.f, 0.f};
    }
    f32x4 accS0 = (f32x4){0.f, 0.f, 0.f, 0.f};
    f32x4 accS1 = (f32x4){0.f, 0.f, 0.f, 0.f};

    // 128 threads stage 8KB K + 8KB V per chunk: 4 dma16 each per array.
    auto stage = [&](int c, int buf) {
        #pragma unroll
        for (int t = 0; t < 4; ++t) {
            int i = tid + t * 128;
            dma16(Kslab + (size_t)c * 4096 + i * 8, Kb + buf * 4096 + t * 1024 + wave * 512);
            dma16(Vslab + (size_t)c * 4096 + i * 8, Vb + buf * 4096 + t * 1024 + wave * 512);
        }
    };

    const bool oddq = (quad & 1) != 0;

    stage(0, 0);
    for (int c = 0; c < 16; ++c) {
        __syncthreads();                          // drains chunk c's DMA; syncs compute c-1
        if (c + 1 < 16) stage(c + 1, (c + 1) & 1);   // in flight during compute of c
        const unsigned short* kb = Kb + (c & 1) * 4096;
        const unsigned short* vb = Vb + (c & 1) * 4096;

        #pragma unroll
        for (int hh = 0; hh < 2; ++hh) {
            // shared K reads for this 32-kv half (4 x b128)
            bf16x8 ka0 = *(const bf16x8*)(kb + (((4 * hh + 0) * 4 + quad) * 16 + l15) * 8);
            bf16x8 ka1 = *(const bf16x8*)(kb + (((4 * hh + 1) * 4 + quad) * 16 + l15) * 8);
            bf16x8 kb0 = *(const bf16x8*)(kb + (((4 * hh + 2) * 4 + quad) * 16 + l15) * 8);
            bf16x8 kb1 = *(const bf16x8*)(kb + (((4 * hh + 3) * 4 + quad) * 16 + l15) * 8);

            // QK^T for both q-fragments (K operands reused)
            f32x4 za0 = (f32x4){0.f, 0.f, 0.f, 0.f};
            za0 = mfma32(ka0, aq0_0, za0);
            za0 = mfma32(ka1, aq1_0, za0);        // kv = 32hh + quad*4 + r, frag 0
            f32x4 zb0 = (f32x4){0.f, 0.f, 0.f, 0.f};
            zb0 = mfma32(kb0, aq0_0, zb0);
            zb0 = mfma32(kb1, aq1_0, zb0);        // kv = 32hh + 16 + quad*4 + r, frag 0
            f32x4 za1 = (f32x4){0.f, 0.f, 0.f, 0.f};
            za1 = mfma32(ka0, aq0_1, za1);
            za1 = mfma32(ka1, aq1_1, za1);        // frag 1
            f32x4 zb1 = (f32x4){0.f, 0.f, 0.f, 0.f};
            zb1 = mfma32(kb0, aq0_1, zb1);
            zb1 = mfma32(kb1, aq1_1, zb1);

            // shared V reads for this half (4 x b128)
            bf16x8 vv0 = *(const bf16x8*)(vb + (((hh * 4 + 0) * 4 + quad) * 16 + l15) * 8);
            bf16x8 vv1 = *(const bf16x8*)(vb + (((hh * 4 + 1) * 4 + quad) * 16 + l15) * 8);
            bf16x8 vv2 = *(const bf16x8*)(vb + (((hh * 4 + 2) * 4 + quad) * 16 + l15) * 8);
            bf16x8 vv3 = *(const bf16x8*)(vb + (((hh * 4 + 3) * 4 + quad) * 16 + l15) * 8);

            #pragma unroll
            for (int f = 0; f < 2; ++f) {
                f32x4 za = f ? za1 : za0;
                f32x4 zb = f ? zb1 : zb0;

                float ea0 = __builtin_amdgcn_exp2f(za[0]); ea0 = (za[0] < 0.f) ? 0.f : ea0;
                float ea1 = __builtin_amdgcn_exp2f(za[1]); ea1 = (za[1] < 0.f) ? 0.f : ea1;
                float ea2 = __builtin_amdgcn_exp2f(za[2]); ea2 = (za[2] < 0.f) ? 0.f : ea2;
                float ea3 = __builtin_amdgcn_exp2f(za[3]); ea3 = (za[3] < 0.f) ? 0.f : ea3;
                float eb0 = __builtin_amdgcn_exp2f(zb[0]); eb0 = (zb[0] < 0.f) ? 0.f : eb0;
                float eb1 = __builtin_amdgcn_exp2f(zb[1]); eb1 = (zb[1] < 0.f) ? 0.f : eb1;
                float eb2 = __builtin_amdgcn_exp2f(zb[2]); eb2 = (zb[2] < 0.f) ? 0.f : eb2;
                float eb3 = __builtin_amdgcn_exp2f(zb[3]); eb3 = (zb[3] < 0.f) ? 0.f : eb3;

                unsigned A0 = cvtpk(ea0, ea1), A1 = cvtpk(ea2, ea3);
                unsigned B0 = cvtpk(eb0, eb1), B1 = cvtpk(eb2, eb3);

                // XOR-16 exchange: even quads keep low-16 kv, odd keep high-16
                // (order baked into vg's layout).
                unsigned send0 = oddq ? A0 : B0, send1 = oddq ? A1 : B1;
                unsigned keep0 = oddq ? B0 : A0, keep1 = oddq ? B1 : A1;
                unsigned rr0 = (unsigned)__shfl_xor((int)send0, 16, 64);
                unsigned rr1 = (unsigned)__shfl_xor((int)send1, 16, 64);

                union { unsigned u[4]; bf16x8 v; } pw;
                pw.u[0] = keep0; pw.u[1] = keep1; pw.u[2] = rr0; pw.u[3] = rr1;

                if (f == 0) {
                    accS0 = mfma32(ONES8, pw.v, accS0);
                    accO0[0] = mfma32(vv0, pw.v, accO0[0]);
                    accO0[1] = mfma32(vv1, pw.v, accO0[1]);
                    accO0[2] = mfma32(vv2, pw.v, accO0[2]);
                    accO0[3] = mfma32(vv3, pw.v, accO0[3]);
                } else {
                    accS1 = mfma32(ONES8, pw.v, accS1);
                    accO1[0] = mfma32(vv0, pw.v, accO1[0]);
                    accO1[1] = mfma32(vv1, pw.v, accO1[1]);
                    accO1[2] = mfma32(vv2, pw.v, accO1[2]);
                    accO1[3] = mfma32(vv3, pw.v, accO1[3]);
                }
            }
        }
    }

    // accS rows identical; lane's col = l15 = its q row within the fragment.
    float inv0 = 1.0f / accS0[0];
    float inv1 = 1.0f / accS1[0];

    unsigned short* orow0 = aout + (rowbase + q0 + l15) * 384 + h * 64 + quad * 4;
    unsigned short* orow1 = orow0 + 16 * 384;
    #pragma unroll
    for (int dt = 0; dt < 4; ++dt) {
        union { unsigned u[2]; ushort4v s; } pk;
        pk.u[0] = cvtpk(accO0[dt][0] * inv0, accO0[dt][1] * inv0);
        pk.u[1] = cvtpk(accO0[dt][2] * inv0, accO0[dt][3] * inv0);
        *(ushort4v*)(orow0 + dt * 16) = pk.s;
        pk.u[0] = cvtpk(accO1[dt][0] * inv1, accO1[dt][1] * inv1);
        pk.u[1] = cvtpk(accO1[dt][2] * inv1, accO1[dt][3] * inv1);
        *(ushort4v*)(orow1 + dt * 16) = pk.s;
    }
}

extern "C" void kernel_launch(void* const* d_in, const int* in_sizes, int n_in,
                              void* d_out, int out_size, void* d_ws, size_t ws_size,
                              hipStream_t stream) {
    const float* x      = (const float*)d_in[0];  // [8,1024,384]
    const float* w_qkv  = (const float*)d_in[1];  // [1152,384]
    const float* b_qkv  = (const float*)d_in[2];  // [1152]
    const float* w_proj = (const float*)d_in[3];  // [384,384]
    const float* b_proj = (const float*)d_in[4];  // [384]
    float* out = (float*)d_out;                   // [8,1024,384]

    unsigned short* qg   = (unsigned short*)d_ws;            // 8192*384
    unsigned short* kgp  = qg   + (size_t)NX;                // 48*65536
    unsigned short* vgp  = kgp  + (size_t)NX;                // 48*65536
    unsigned short* aout = vgp  + (size_t)NX;                // 8192*384
    unsigned short* xb   = aout + (size_t)NX;                // 8192*384
    unsigned short* wqb  = xb   + (size_t)NX;                // 1152*384
    unsigned short* wpb  = wqb  + (size_t)NQ;                // 384*384

    cvt_bf16<<<3648, 256, 0, stream>>>(x, w_qkv, w_proj, xb, wqb, wpb);
    gemm_bt<0, 128><<<dim3(64, 9), 256, 0, stream>>>(
        xb, wqb, b_qkv, qg, kgp, vgp, nullptr, 8192, 1152, 384);
    attn_fused<<<768, 128, 0, stream>>>(qg, kgp, vgp, aout);
    gemm_bt<1, 64><<<dim3(128, 3), 128, 0, stream>>>(
        aout, wpb, b_proj, nullptr, nullptr, nullptr, out, 8192, 384, 384);
}

// Round 5
// 133.458 us; speedup vs baseline: 1.0714x; 1.0714x over previous
//
#include <hip/hip_runtime.h>
#include <hip/hip_bf16.h>

// R13 = R11 compute shapes + counted-vmcnt deep pipeline (T3/T4) in all three
// MFMA kernels. R12's rocprof showed attn latency-bound (MfmaUtil 11%, VALU 25%,
// HBM 4%, occ 12%): the __syncthreads vmcnt(0) drain stalls every chunk.
//  - attn: back to 4 waves x 16 q (768 blocks x 256 thr = 3/CU, 12 waves/CU),
//    TRIPLE-buffered K/V (48KB), prefetch depth 2, per-iter
//    `s_waitcnt vmcnt(4) lgkmcnt(0)` + raw s_barrier (vmcnt counts in issue
//    order -> 4 = own DMAs of the newest chunk stay in flight).
//  - gemm_bt: same pipeline, 3 LDS buffers, depth 2, S = 2 + 512/(TM*2).
//  - QKV TM=128 @(64,9)x256thr; proj TM=64 @(128,3)x128thr (R12 config, neutral).
// Layouts (qg *QSCALE row-major, kg operand-order, vg shuffle-permuted mfma32
// order) unchanged from R11. ws 32.5 MB unchanged.

typedef __attribute__((__ext_vector_type__(8))) __bf16 bf16x8;
typedef __attribute__((__ext_vector_type__(8))) unsigned short ushort8;
typedef __attribute__((__ext_vector_type__(4))) unsigned short ushort4v;
typedef __attribute__((__ext_vector_type__(4))) short short4v;
typedef __attribute__((__ext_vector_type__(4))) float f32x4;

#define NX 3145728   // 8192*384
#define NQ 442368    // 1152*384
#define NP 147456    // 384*384

// 0.125 * log2(e): folds the exp->exp2 conversion into the Q scale.
#define QSCALE 0.1803368801111204f

__device__ __forceinline__ f32x4 mfma32(bf16x8 a, bf16x8 b, f32x4 c) {
    return __builtin_amdgcn_mfma_f32_16x16x32_bf16(a, b, c, 0, 0, 0);
}

__device__ __forceinline__ unsigned short f2bf(float f) {
    union { float f; unsigned int i; } x; x.f = f;
    unsigned int u = x.i;
    return (unsigned short)((u + 0x7fffu + ((u >> 16) & 1u)) >> 16);
}

// pack two f32 -> one u32 of 2 bf16 (RNE) on the VALU cvt pipe
__device__ __forceinline__ unsigned cvtpk(float a, float b) {
    unsigned r;
    asm("v_cvt_pk_bf16_f32 %0, %1, %2" : "=v"(r) : "v"(a), "v"(b));
    return r;
}

__device__ __forceinline__ void dma16(const unsigned short* g, unsigned short* l) {
    __builtin_amdgcn_global_load_lds(
        (const __attribute__((address_space(1))) unsigned int*)g,
        (__attribute__((address_space(3))) unsigned int*)l, 16, 0, 0);
}

// fp32 -> bf16 for x, w_qkv, w_proj. 4 elems/thread.
__global__ __launch_bounds__(256) void cvt_bf16(
    const float* __restrict__ x, const float* __restrict__ wq, const float* __restrict__ wp,
    unsigned short* __restrict__ xb, unsigned short* __restrict__ wqb, unsigned short* __restrict__ wpb)
{
    int i = blockIdx.x * 256 + threadIdx.x;
    const float* src; unsigned short* dst; int off;
    if (i < NX / 4)              { src = x;  dst = xb;  off = i * 4; }
    else if (i < (NX + NQ) / 4)  { src = wq; dst = wqb; off = i * 4 - NX; }
    else                         { src = wp; dst = wpb; off = i * 4 - NX - NQ; }
    float4 v = *(const float4*)(src + off);
    ushort4v r;
    r[0] = f2bf(v.x); r[1] = f2bf(v.y); r[2] = f2bf(v.z); r[3] = f2bf(v.w);
    *(ushort4v*)(dst + off) = r;
}

// C = A[M,K] @ B[N,K]^T + bias. bf16 in, fp32 acc, TMx128 tile, BK=32.
// Counted-vmcnt pipeline: 3 LDS buffers, prefetch depth 2, raw s_barrier.
// THREADS = 2*TM. S (own DMAs per stage) = 2 + 512/(TM*2).
template <int MODE, int TM>
__global__ __launch_bounds__(TM * 2) void gemm_bt(
    const unsigned short* __restrict__ A,
    const unsigned short* __restrict__ B,
    const float* __restrict__ bias,
    unsigned short* __restrict__ qg,
    unsigned short* __restrict__ kg,
    unsigned short* __restrict__ vg,
    float* __restrict__ out,
    int M, int N, int K)
{
    const int tid  = threadIdx.x;
    const int lane = tid & 63;
    const int wave = tid >> 6;
    const int l15  = lane & 15;
    const int quad = lane >> 4;
    const int m0 = blockIdx.x * TM;
    const int n0 = blockIdx.y * 128;
    const int wm = (wave >> 1) * 64;
    const int wn = (wave & 1) * 64;

    __shared__ __align__(16) unsigned short As[3 * TM * 32];
    __shared__ __align__(16) unsigned short Bs[3 * 128 * 32];

    f32x4 acc[4][4];
    #pragma unroll
    for (int i = 0; i < 4; ++i)
        #pragma unroll
        for (int j = 0; j < 4; ++j)
            acc[i][j] = (f32x4){0.f, 0.f, 0.f, 0.f};

    // stage K-slice k0 into buffer buf (S = 2 + 512/(TM*2) dma16 per thread)
    auto stage = [&](int k0, int buf) {
        #pragma unroll
        for (int t = 0; t < 2; ++t) {
            int i = tid + t * TM * 2;
            dma16(A + (size_t)(m0 + (i >> 2)) * K + k0 + (i & 3) * 8,
                  As + buf * TM * 32 + t * TM * 16 + wave * 512);
        }
        #pragma unroll
        for (int t = 0; t < 512 / (TM * 2); ++t) {
            int i = tid + t * TM * 2;
            dma16(B + (size_t)(n0 + (i >> 2)) * K + k0 + (i & 3) * 8,
                  Bs + buf * 4096 + t * TM * 16 + wave * 512);
        }
    };

    constexpr int S = 2 + 512 / (TM * 2);
    const int nk = K >> 5;   // 12
    stage(0, 0);
    stage(32, 1);
    for (int ki = 0; ki < nk; ++ki) {
        // own chunk-ki DMAs drained (issue-order vmcnt), newest chunk stays in
        // flight; lgkmcnt(0): my LDS reads of ki-1 are in registers.
        if (ki + 1 < nk) {
            if constexpr (S == 3)      asm volatile("s_waitcnt vmcnt(3) lgkmcnt(0)" ::: "memory");
            else if constexpr (S == 4) asm volatile("s_waitcnt vmcnt(4) lgkmcnt(0)" ::: "memory");
            else                       asm volatile("s_waitcnt vmcnt(6) lgkmcnt(0)" ::: "memory");
        } else {
            asm volatile("s_waitcnt vmcnt(0) lgkmcnt(0)" ::: "memory");
        }
        __builtin_amdgcn_s_barrier();
        __builtin_amdgcn_sched_barrier(0);
        if (ki + 2 < nk) stage((ki + 2) << 5, (ki + 2) % 3);   // buf of ki-1, all done with it

        const unsigned short* as = As + (ki % 3) * TM * 32;
        const unsigned short* bs = Bs + (ki % 3) * 4096;

        bf16x8 af[4], bff[4];
        #pragma unroll
        for (int mt = 0; mt < 4; ++mt)
            af[mt] = *(const bf16x8*)(as + (wm + mt * 16 + l15) * 32 + quad * 8);
        #pragma unroll
        for (int nt = 0; nt < 4; ++nt)
            bff[nt] = *(const bf16x8*)(bs + (wn + nt * 16 + l15) * 32 + quad * 8);
        #pragma unroll
        for (int mt = 0; mt < 4; ++mt)
            #pragma unroll
            for (int nt = 0; nt < 4; ++nt)
                acc[mt][nt] = mfma32(af[mt], bff[nt], acc[mt][nt]);
    }

    if constexpr (MODE == 0) {
        if (n0 < 384) {            // Q region: row-major, pre-scaled by 0.125*log2e
            #pragma unroll
            for (int nt = 0; nt < 4; ++nt) {
                int n = n0 + wn + nt * 16 + l15;
                float bv = bias[n];
                #pragma unroll
                for (int mt = 0; mt < 4; ++mt) {
                    int mbase = m0 + wm + mt * 16 + quad * 4;
                    #pragma unroll
                    for (int r = 0; r < 4; ++r)
                        qg[(size_t)(mbase + r) * 384 + n] = f2bf((acc[mt][nt][r] + bv) * QSCALE);
                }
            }
        } else if (n0 < 768) {     // K region: operand-order slabs
            #pragma unroll
            for (int nt = 0; nt < 4; ++nt) {
                int n = n0 + wn + nt * 16 + l15;
                float bv = bias[n];
                int c2 = n - 384;
                int h = c2 >> 6, ck = c2 & 63;
                int half = ck >> 5, qd = (ck >> 3) & 3, j = ck & 7;
                #pragma unroll
                for (int mt = 0; mt < 4; ++mt) {
                    int mbase = m0 + wm + mt * 16 + quad * 4;
                    #pragma unroll
                    for (int r = 0; r < 4; ++r) {
                        int tok = mbase + r;
                        int b = tok >> 10, kv = tok & 1023;
                        int kt = kv >> 4, lk = kv & 15;
                        kg[(size_t)(b * 6 + h) * 65536 +
                           ((((size_t)kt * 2 + half) * 4 + qd) * 16 + lk) * 8 + j]
                            = f2bf(acc[mt][nt][r] + bv);
                    }
                }
            }
        } else {                   // V region: shuffle-permuted mfma32 operand order
            #pragma unroll
            for (int nt = 0; nt < 4; ++nt) {
                int n = n0 + wn + nt * 16 + l15;
                float bv = bias[n];
                int c2 = n - 768;
                int h = c2 >> 6, d = c2 & 63;
                int dt = d >> 4, lv = d & 15;
                #pragma unroll
                for (int mt = 0; mt < 4; ++mt) {
                    int mbase = m0 + wm + mt * 16 + quad * 4;   // multiple of 4
                    int b = mbase >> 10, kvb = mbase & 1023;
                    int cc = kvb >> 6;
                    int hh = (kvb >> 5) & 1;
                    int rem2 = kvb & 31;                         // multiple of 4
                    int qv, j;
                    if (rem2 < 16) { qv = (rem2 >> 3) << 1; j = rem2 & 7; }
                    else {
                        int m2 = rem2 - 16;
                        qv = 1 + ((m2 >> 3) << 1);
                        j = (((m2 >> 2) & 1) ^ 1) << 2;          // m2 multiple of 4
                    }
                    ushort4v pk;
                    #pragma unroll
                    for (int r = 0; r < 4; ++r) pk[r] = f2bf(acc[mt][nt][r] + bv);
                    *(ushort4v*)(vg + (size_t)(b * 6 + h) * 65536 +
                                 ((((size_t)cc * 2 + hh) * 4 + dt) * 4 + qv) * 128 + lv * 8 + j) = pk;
                }
            }
        }
    } else {
        #pragma unroll
        for (int nt = 0; nt < 4; ++nt) {
            int n = n0 + wn + nt * 16 + l15;
            float bv = bias[n];
            #pragma unroll
            for (int mt = 0; mt < 4; ++mt) {
                int mbase = m0 + wm + mt * 16 + quad * 4;
                #pragma unroll
                for (int r = 0; r < 4; ++r)
                    out[(size_t)(mbase + r) * N + n] = acc[mt][nt][r] + bv;
            }
        }
    }
}

// Flash attention: 4 waves x 16 q (R11 shape, 12 waves/CU), counted-vmcnt
// pipeline: 3 K/V buffers (48KB LDS), prefetch depth 2, per-iter
// `s_waitcnt vmcnt(4) lgkmcnt(0)` + raw s_barrier. kv-chunk 64.
// All-mfma32: per 32-kv half 4 QK mfma -> 8 exp2+mask -> 4 cvt_pk ->
// 2 shfl_xor -> 1 rowsum + 4 PV mfma (permutation baked into vg).
__global__ __launch_bounds__(256) void attn_fused(
    const unsigned short* __restrict__ qg,
    const unsigned short* __restrict__ kg,
    const unsigned short* __restrict__ vg,
    unsigned short* __restrict__ aout)   // [8192][384] bf16
{
    const int tid  = threadIdx.x;
    const int wave = tid >> 6;
    const int lane = tid & 63;
    const int l15  = lane & 15;
    const int quad = lane >> 4;
    const int id = blockIdx.x;
    const int s  = id % 48;      // slab = b*6+h  (id%8 == s%8 -> same XCD per slab)
    const int qt = id / 48;      // 0..15
    const int b  = s / 6;
    const int h  = s % 6;

    const size_t rowbase = (size_t)b * 1024;
    const unsigned short* Kslab = kg + (size_t)s * 65536;
    const unsigned short* Vslab = vg + (size_t)s * 65536;
    const int q0 = qt * 64 + wave * 16;

    __shared__ __align__(16) unsigned short Kb[3 * 4096];
    __shared__ __align__(16) unsigned short Vb[3 * 4096];

    bf16x8 aq0, aq1;
    {
        const unsigned short* qrow = qg + (rowbase + q0 + l15) * 384 + h * 64 + quad * 8;
        aq0 = *(const bf16x8*)qrow;
        aq1 = *(const bf16x8*)(qrow + 32);
    }

    union { unsigned short us[8]; bf16x8 v; } ones_u;
    #pragma unroll
    for (int i = 0; i < 8; ++i) ones_u.us[i] = 0x3F80;
    const bf16x8 ONES8 = ones_u.v;

    f32x4 accO[4];
    #pragma unroll
    for (int dt = 0; dt < 4; ++dt) accO[dt] = (f32x4){0.f, 0.f, 0.f, 0.f};
    f32x4 accS = (f32x4){0.f, 0.f, 0.f, 0.f};   // row-sum of P (all 4 rows identical)

    // 4 dma16/thread per chunk (2 K + 2 V)
    auto stage = [&](int c, int buf) {
        #pragma unroll
        for (int t = 0; t < 2; ++t) {
            int i = tid + t * 256;
            dma16(Kslab + (size_t)c * 4096 + i * 8, Kb + buf * 4096 + t * 2048 + wave * 512);
            dma16(Vslab + (size_t)c * 4096 + i * 8, Vb + buf * 4096 + t * 2048 + wave * 512);
        }
    };

    const bool oddq = (quad & 1) != 0;

    stage(0, 0);
    stage(1, 1);
    for (int c = 0; c < 16; ++c) {
        if (c < 15) asm volatile("s_waitcnt vmcnt(4) lgkmcnt(0)" ::: "memory");
        else        asm volatile("s_waitcnt vmcnt(0) lgkmcnt(0)" ::: "memory");
        __builtin_amdgcn_s_barrier();
        __builtin_amdgcn_sched_barrier(0);
        if (c + 2 < 16) stage(c + 2, (c + 2) % 3);   // reuses buf of c-1, all waves done

        const unsigned short* kb = Kb + (c % 3) * 4096;
        const unsigned short* vb = Vb + (c % 3) * 4096;

        #pragma unroll
        for (int hh = 0; hh < 2; ++hh) {
            // QK^T for the two 16-kv tiles of this 32-kv half
            bf16x8 ka0 = *(const bf16x8*)(kb + (((4 * hh + 0) * 4 + quad) * 16 + l15) * 8);
            bf16x8 ka1 = *(const bf16x8*)(kb + (((4 * hh + 1) * 4 + quad) * 16 + l15) * 8);
            f32x4 za = (f32x4){0.f, 0.f, 0.f, 0.f};
            za = mfma32(ka0, aq0, za);
            za = mfma32(ka1, aq1, za);            // kv = 32hh + quad*4 + r
            bf16x8 kb0 = *(const bf16x8*)(kb + (((4 * hh + 2) * 4 + quad) * 16 + l15) * 8);
            bf16x8 kb1 = *(const bf16x8*)(kb + (((4 * hh + 3) * 4 + quad) * 16 + l15) * 8);
            f32x4 zb = (f32x4){0.f, 0.f, 0.f, 0.f};
            zb = mfma32(kb0, aq0, zb);
            zb = mfma32(kb1, aq1, zb);            // kv = 32hh + 16 + quad*4 + r

            // threshold mask -> exact 0, exp2 on trans pipe (Q pre-scaled by log2e)
            float ea0 = __builtin_amdgcn_exp2f(za[0]); ea0 = (za[0] < 0.f) ? 0.f : ea0;
            float ea1 = __builtin_amdgcn_exp2f(za[1]); ea1 = (za[1] < 0.f) ? 0.f : ea1;
            float ea2 = __builtin_amdgcn_exp2f(za[2]); ea2 = (za[2] < 0.f) ? 0.f : ea2;
            float ea3 = __builtin_amdgcn_exp2f(za[3]); ea3 = (za[3] < 0.f) ? 0.f : ea3;
            float eb0 = __builtin_amdgcn_exp2f(zb[0]); eb0 = (zb[0] < 0.f) ? 0.f : eb0;
            float eb1 = __builtin_amdgcn_exp2f(zb[1]); eb1 = (zb[1] < 0.f) ? 0.f : eb1;
            float eb2 = __builtin_amdgcn_exp2f(zb[2]); eb2 = (zb[2] < 0.f) ? 0.f : eb2;
            float eb3 = __builtin_amdgcn_exp2f(zb[3]); eb3 = (zb[3] < 0.f) ? 0.f : eb3;

            unsigned A0 = cvtpk(ea0, ea1), A1 = cvtpk(ea2, ea3);
            unsigned B0 = cvtpk(eb0, eb1), B1 = cvtpk(eb2, eb3);

            // XOR-16 exchange: even quads keep low-16 kv, odd keep high-16
            // (order baked into vg's layout).
            unsigned send0 = oddq ? A0 : B0, send1 = oddq ? A1 : B1;
            unsigned keep0 = oddq ? B0 : A0, keep1 = oddq ? B1 : A1;
            unsigned rr0 = (unsigned)__shfl_xor((int)send0, 16, 64);
            unsigned rr1 = (unsigned)__shfl_xor((int)send1, 16, 64);

            union { unsigned u[4]; bf16x8 v; } pw;
            pw.u[0] = keep0; pw.u[1] = keep1; pw.u[2] = rr0; pw.u[3] = rr1;

            accS = mfma32(ONES8, pw.v, accS);     // row-sum on matrix pipe
            #pragma unroll
            for (int dt = 0; dt < 4; ++dt) {
                bf16x8 vv = *(const bf16x8*)(vb + (((hh * 4 + dt) * 4 + quad) * 16 + l15) * 8);
                accO[dt] = mfma32(vv, pw.v, accO[dt]);
            }
        }
    }

    // accS rows identical; lane's col = l15 = its q row. No shuffles needed.
    float inv = 1.0f / accS[0];

    unsigned short* orow = aout + (rowbase + q0 + l15) * 384 + h * 64 + quad * 4;
    #pragma unroll
    for (int dt = 0; dt < 4; ++dt) {
        union { unsigned u[2]; ushort4v s; } pk;
        pk.u[0] = cvtpk(accO[dt][0] * inv, accO[dt][1] * inv);
        pk.u[1] = cvtpk(accO[dt][2] * inv, accO[dt][3] * inv);
        *(ushort4v*)(orow + dt * 16) = pk.s;
    }
}

extern "C" void kernel_launch(void* const* d_in, const int* in_sizes, int n_in,
                              void* d_out, int out_size, void* d_ws, size_t ws_size,
                              hipStream_t stream) {
    const float* x      = (const float*)d_in[0];  // [8,1024,384]
    const float* w_qkv  = (const float*)d_in[1];  // [1152,384]
    const float* b_qkv  = (const float*)d_in[2];  // [1152]
    const float* w_proj = (const float*)d_in[3];  // [384,384]
    const float* b_proj = (const float*)d_in[4];  // [384]
    float* out = (float*)d_out;                   // [8,1024,384]

    unsigned short* qg   = (unsigned short*)d_ws;            // 8192*384
    unsigned short* kgp  = qg   + (size_t)NX;                // 48*65536
    unsigned short* vgp  = kgp  + (size_t)NX;                // 48*65536
    unsigned short* aout = vgp  + (size_t)NX;                // 8192*384
    unsigned short* xb   = aout + (size_t)NX;                // 8192*384
    unsigned short* wqb  = xb   + (size_t)NX;                // 1152*384
    unsigned short* wpb  = wqb  + (size_t)NQ;                // 384*384

    cvt_bf16<<<3648, 256, 0, stream>>>(x, w_qkv, w_proj, xb, wqb, wpb);
    gemm_bt<0, 128><<<dim3(64, 9), 256, 0, stream>>>(
        xb, wqb, b_qkv, qg, kgp, vgp, nullptr, 8192, 1152, 384);
    attn_fused<<<768, 256, 0, stream>>>(qg, kgp, vgp, aout);
    gemm_bt<1, 64><<<dim3(128, 3), 128, 0, stream>>>(
        aout, wpb, b_proj, nullptr, nullptr, nullptr, out, 8192, 384, 384);
}